// Round 1
// baseline (3161.834 us; speedup 1.0000x reference)
//
#include <hip/hip_runtime.h>

#define NN 50000
#define NE 800000
#define C_IN 128
#define C_H 128
#define C_OUT 16
#define BN_EPS 1e-5f

// ---------------- degree ----------------
__global__ void k_deg(const int* __restrict__ dst, int* __restrict__ deg) {
    int e = blockIdx.x * blockDim.x + threadIdx.x;
    if (e < NE) atomicAdd(&deg[dst[e]], 1);
}

__global__ void k_dinv(const int* __restrict__ deg, float* __restrict__ dinv) {
    int i = blockIdx.x * blockDim.x + threadIdx.x;
    if (i < NN) dinv[i] = rsqrtf((float)(deg[i] + 1));  // +1 self-loop; >=1 always
}

// ---------------- GEMM 128x128, output scaled by dinv[row] ----------------
// block = 256 threads, 32 rows/block. W (64KB) + X rows (16KB) in LDS.
__global__ __launch_bounds__(256) void k_gemm128_scaled(
    const float* __restrict__ X, const float* __restrict__ W,
    const float* __restrict__ dinv, float* __restrict__ Y) {
    __shared__ float Wl[128 * 128];
    __shared__ float Xs[32 * 128];
    int t = threadIdx.x;
    {
        const float4* Wv = (const float4*)W;
        float4* Wlv = (float4*)Wl;
        for (int i = t; i < 4096; i += 256) Wlv[i] = Wv[i];
    }
    int row0 = blockIdx.x * 32;
    int nrow = min(32, NN - row0);
    {
        const float4* Xv = (const float4*)(X + (size_t)row0 * 128);
        float4* Xsv = (float4*)Xs;
        for (int i = t; i < nrow * 32; i += 256) Xsv[i] = Xv[i];
    }
    __syncthreads();
    int c = t & 127;
    int rl = t >> 7;  // 0/1, wave-uniform
    float acc[16];
#pragma unroll
    for (int j = 0; j < 16; ++j) acc[j] = 0.f;
    for (int k = 0; k < 128; ++k) {
        float w = Wl[k * 128 + c];
#pragma unroll
        for (int j = 0; j < 16; ++j) acc[j] += Xs[(j * 2 + rl) * 128 + k] * w;
    }
    float* yp = Y + (size_t)row0 * 128;
#pragma unroll
    for (int j = 0; j < 16; ++j) {
        int r = j * 2 + rl;
        if (r < nrow) yp[r * 128 + c] = acc[j] * dinv[row0 + r];
    }
}

// ---------------- GEMM 128x16, output scaled by dinv[row] ----------------
// block = 256 threads, 64 rows/block.
__global__ __launch_bounds__(256) void k_gemm16_scaled(
    const float* __restrict__ X, const float* __restrict__ W,
    const float* __restrict__ dinv, float* __restrict__ Y) {
    __shared__ float Wl[128 * 16];
    __shared__ float Xs[64 * 128];
    int t = threadIdx.x;
    {
        const float4* Wv = (const float4*)W;
        float4* Wlv = (float4*)Wl;
        for (int i = t; i < 512; i += 256) Wlv[i] = Wv[i];
    }
    int row0 = blockIdx.x * 64;
    int nrow = min(64, NN - row0);
    {
        const float4* Xv = (const float4*)(X + (size_t)row0 * 128);
        float4* Xsv = (float4*)Xs;
        for (int i = t; i < nrow * 32; i += 256) Xsv[i] = Xv[i];
    }
    __syncthreads();
    int c = t & 15;
    int rl = t >> 4;  // 0..15
    float acc[4] = {0.f, 0.f, 0.f, 0.f};
    for (int k = 0; k < 128; ++k) {
        float w = Wl[k * 16 + c];
#pragma unroll
        for (int j = 0; j < 4; ++j) acc[j] += Xs[(rl + j * 16) * 128 + k] * w;
    }
#pragma unroll
    for (int j = 0; j < 4; ++j) {
        int r = rl + j * 16;
        if (r < nrow) Y[(size_t)(row0 + r) * 16 + c] = acc[j] * dinv[row0 + r];
    }
}

// ---------------- edge scatter: O[dst] += Ts[src] ----------------
// 32 threads per edge, float4 chunks (128 ch)
__global__ void k_scatter128(const int* __restrict__ src, const int* __restrict__ dst,
                             const float* __restrict__ Ts, float* __restrict__ O) {
    int gid = blockIdx.x * blockDim.x + threadIdx.x;
    int e = gid >> 5;
    int c4 = gid & 31;
    if (e >= NE) return;
    int s = src[e], d = dst[e];
    float4 v = ((const float4*)(Ts + (size_t)s * 128))[c4];
    float* o = O + (size_t)d * 128 + c4 * 4;
    atomicAdd(o + 0, v.x);
    atomicAdd(o + 1, v.y);
    atomicAdd(o + 2, v.z);
    atomicAdd(o + 3, v.w);
}

// 4 threads per edge, float4 chunks (16 ch)
__global__ void k_scatter16(const int* __restrict__ src, const int* __restrict__ dst,
                            const float* __restrict__ Ts, float* __restrict__ O) {
    int gid = blockIdx.x * blockDim.x + threadIdx.x;
    int e = gid >> 2;
    int c4 = gid & 3;
    if (e >= NE) return;
    int s = src[e], d = dst[e];
    float4 v = ((const float4*)(Ts + (size_t)s * 16))[c4];
    float* o = O + (size_t)d * 16 + c4 * 4;
    atomicAdd(o + 0, v.x);
    atomicAdd(o + 1, v.y);
    atomicAdd(o + 2, v.z);
    atomicAdd(o + 3, v.w);
}

// ---------------- finalize: h = dinv*O + b; z = relu(bn(h)) ----------------
__global__ void k_bnrelu(const float* __restrict__ O, const float* __restrict__ dinv,
                         const float* __restrict__ b, const float* __restrict__ g,
                         const float* __restrict__ beta, const float* __restrict__ m,
                         const float* __restrict__ v, float* __restrict__ Z) {
    int idx = blockIdx.x * blockDim.x + threadIdx.x;
    if (idx >= NN * 128) return;
    int i = idx >> 7, c = idx & 127;
    float h = O[idx] * dinv[i] + b[c];
    float y = (h - m[c]) * rsqrtf(v[c] + BN_EPS) * g[c] + beta[c];
    Z[idx] = fmaxf(y, 0.f);
}

// ---------------- finalize layer 3: logits + log_softmax (in place) ----------------
__global__ void k_logsoftmax(float* __restrict__ O, const float* __restrict__ dinv,
                             const float* __restrict__ b3) {
    int i = blockIdx.x * blockDim.x + threadIdx.x;
    if (i >= NN) return;
    float di = dinv[i];
    float vals[16];
    float4* op = (float4*)(O + (size_t)i * 16);
    float4 t0 = op[0], t1 = op[1], t2 = op[2], t3 = op[3];
    vals[0] = t0.x; vals[1] = t0.y; vals[2] = t0.z; vals[3] = t0.w;
    vals[4] = t1.x; vals[5] = t1.y; vals[6] = t1.z; vals[7] = t1.w;
    vals[8] = t2.x; vals[9] = t2.y; vals[10] = t2.z; vals[11] = t2.w;
    vals[12] = t3.x; vals[13] = t3.y; vals[14] = t3.z; vals[15] = t3.w;
    float mx = -1e30f;
#pragma unroll
    for (int c = 0; c < 16; ++c) {
        vals[c] = vals[c] * di + b3[c];
        mx = fmaxf(mx, vals[c]);
    }
    float se = 0.f;
#pragma unroll
    for (int c = 0; c < 16; ++c) se += expf(vals[c] - mx);
    float lse = mx + logf(se);
    op[0] = make_float4(vals[0] - lse, vals[1] - lse, vals[2] - lse, vals[3] - lse);
    op[1] = make_float4(vals[4] - lse, vals[5] - lse, vals[6] - lse, vals[7] - lse);
    op[2] = make_float4(vals[8] - lse, vals[9] - lse, vals[10] - lse, vals[11] - lse);
    op[3] = make_float4(vals[12] - lse, vals[13] - lse, vals[14] - lse, vals[15] - lse);
}

extern "C" void kernel_launch(void* const* d_in, const int* in_sizes, int n_in,
                              void* d_out, int out_size, void* d_ws, size_t ws_size,
                              hipStream_t stream) {
    const float* x  = (const float*)d_in[0];
    const int* ei   = (const int*)d_in[1];
    const float* W1 = (const float*)d_in[2];
    const float* b1 = (const float*)d_in[3];
    const float* g1 = (const float*)d_in[4];
    const float* be1 = (const float*)d_in[5];
    const float* m1 = (const float*)d_in[6];
    const float* v1 = (const float*)d_in[7];
    const float* W2 = (const float*)d_in[8];
    const float* b2 = (const float*)d_in[9];
    const float* g2 = (const float*)d_in[10];
    const float* be2 = (const float*)d_in[11];
    const float* m2 = (const float*)d_in[12];
    const float* v2 = (const float*)d_in[13];
    const float* W3 = (const float*)d_in[14];
    const float* b3 = (const float*)d_in[15];
    float* out = (float*)d_out;

    char* ws = (char*)d_ws;
    size_t off = 0;
    auto alloc = [&](size_t bytes) {
        char* p = ws + off;
        off = (off + bytes + 255) & ~255ULL;
        return p;
    };
    float* dinv = (float*)alloc((size_t)NN * 4);
    int* degi   = (int*)alloc((size_t)NN * 4);
    float* bufA = (float*)alloc((size_t)NN * 128 * 4);
    float* bufB = (float*)alloc((size_t)NN * 128 * 4);
    float* bufC = (float*)alloc((size_t)NN * 16 * 4);

    const int* srcp = ei;
    const int* dstp = ei + NE;

    hipMemsetAsync(degi, 0, (size_t)NN * 4, stream);
    k_deg<<<(NE + 255) / 256, 256, 0, stream>>>(dstp, degi);
    k_dinv<<<(NN + 255) / 256, 256, 0, stream>>>(degi, dinv);

    // ---- layer 1 ----
    k_gemm128_scaled<<<(NN + 31) / 32, 256, 0, stream>>>(x, W1, dinv, bufA);
    hipMemcpyAsync(bufB, bufA, (size_t)NN * 128 * 4, hipMemcpyDeviceToDevice, stream);
    k_scatter128<<<(NE * 32 + 255) / 256, 256, 0, stream>>>(srcp, dstp, bufA, bufB);
    k_bnrelu<<<((size_t)NN * 128 + 255) / 256, 256, 0, stream>>>(bufB, dinv, b1, g1, be1, m1, v1, bufA);

    // ---- layer 2 ----
    k_gemm128_scaled<<<(NN + 31) / 32, 256, 0, stream>>>(bufA, W2, dinv, bufB);
    hipMemcpyAsync(bufA, bufB, (size_t)NN * 128 * 4, hipMemcpyDeviceToDevice, stream);
    k_scatter128<<<(NE * 32 + 255) / 256, 256, 0, stream>>>(srcp, dstp, bufB, bufA);
    k_bnrelu<<<((size_t)NN * 128 + 255) / 256, 256, 0, stream>>>(bufA, dinv, b2, g2, be2, m2, v2, bufB);

    // ---- layer 3 ----
    k_gemm16_scaled<<<(NN + 63) / 64, 256, 0, stream>>>(bufB, W3, dinv, bufC);
    hipMemcpyAsync(out, bufC, (size_t)NN * 16 * 4, hipMemcpyDeviceToDevice, stream);
    k_scatter16<<<(NE * 4 + 255) / 256, 256, 0, stream>>>(srcp, dstp, bufC, out);
    k_logsoftmax<<<(NN + 255) / 256, 256, 0, stream>>>(out, dinv, b3);
}

// Round 2
// 479.136 us; speedup vs baseline: 6.5990x; 6.5990x over previous
//
#include <hip/hip_runtime.h>

#define NN 50000
#define NE 800000
#define NB 196          // (NN+255)/256
#define BN_EPS 1e-5f

// ---------------- degree ----------------
__global__ void k_deg(const int* __restrict__ dst, int* __restrict__ deg) {
    int e = blockIdx.x * blockDim.x + threadIdx.x;
    if (e < NE) atomicAdd(&deg[dst[e]], 1);
}

__global__ void k_dinv(const int* __restrict__ deg, float* __restrict__ dinv) {
    int i = blockIdx.x * blockDim.x + threadIdx.x;
    if (i < NN) dinv[i] = rsqrtf((float)(deg[i] + 1));  // +1 self-loop
}

// ---------------- exclusive scan (3-kernel hierarchical) ----------------
__global__ __launch_bounds__(256) void k_scan1(const int* __restrict__ deg,
                                               int* __restrict__ rowptr,
                                               int* __restrict__ bsum) {
    __shared__ int s[256];
    int t = threadIdx.x;
    int i = blockIdx.x * 256 + t;
    int v = (i < NN) ? deg[i] : 0;
    s[t] = v;
    __syncthreads();
    for (int off = 1; off < 256; off <<= 1) {
        int add = (t >= off) ? s[t - off] : 0;
        __syncthreads();
        s[t] += add;
        __syncthreads();
    }
    if (i < NN) rowptr[i] = s[t] - v;  // exclusive partial
    if (t == 255) bsum[blockIdx.x] = s[255];
}

__global__ __launch_bounds__(256) void k_scan2(int* __restrict__ bsum) {
    __shared__ int s[256];
    int t = threadIdx.x;
    int v = (t < NB) ? bsum[t] : 0;
    s[t] = v;
    __syncthreads();
    for (int off = 1; off < 256; off <<= 1) {
        int add = (t >= off) ? s[t - off] : 0;
        __syncthreads();
        s[t] += add;
        __syncthreads();
    }
    if (t < NB) bsum[t] = s[t] - v;  // exclusive
}

__global__ __launch_bounds__(256) void k_scan3(int* __restrict__ rowptr,
                                               const int* __restrict__ bsum,
                                               int* __restrict__ cursor) {
    int i = blockIdx.x * 256 + threadIdx.x;
    if (i < NN) {
        int r = rowptr[i] + bsum[blockIdx.x];
        rowptr[i] = r;
        cursor[i] = r;
    }
    if (i == 0) rowptr[NN] = NE;
}

// ---------------- CSR fill: bucket edges by dst ----------------
__global__ void k_csrfill(const int* __restrict__ src, const int* __restrict__ dst,
                          int* __restrict__ cursor, int* __restrict__ eidx) {
    int e = blockIdx.x * blockDim.x + threadIdx.x;
    if (e >= NE) return;
    int d = dst[e];
    int pos = atomicAdd(&cursor[d], 1);
    eidx[pos] = src[e];
}

// ---------------- GEMM 128x128, output scaled by dinv[row] ----------------
__global__ __launch_bounds__(256) void k_gemm128_scaled(
    const float* __restrict__ X, const float* __restrict__ W,
    const float* __restrict__ dinv, float* __restrict__ Y) {
    __shared__ float Wl[128 * 128];
    __shared__ float Xs[32 * 128];
    int t = threadIdx.x;
    {
        const float4* Wv = (const float4*)W;
        float4* Wlv = (float4*)Wl;
        for (int i = t; i < 4096; i += 256) Wlv[i] = Wv[i];
    }
    int row0 = blockIdx.x * 32;
    int nrow = min(32, NN - row0);
    {
        const float4* Xv = (const float4*)(X + (size_t)row0 * 128);
        float4* Xsv = (float4*)Xs;
        for (int i = t; i < nrow * 32; i += 256) Xsv[i] = Xv[i];
    }
    __syncthreads();
    int c = t & 127;
    int rl = t >> 7;
    float acc[16];
#pragma unroll
    for (int j = 0; j < 16; ++j) acc[j] = 0.f;
    for (int k = 0; k < 128; ++k) {
        float w = Wl[k * 128 + c];
#pragma unroll
        for (int j = 0; j < 16; ++j) acc[j] += Xs[(j * 2 + rl) * 128 + k] * w;
    }
    float* yp = Y + (size_t)row0 * 128;
#pragma unroll
    for (int j = 0; j < 16; ++j) {
        int r = j * 2 + rl;
        if (r < nrow) yp[r * 128 + c] = acc[j] * dinv[row0 + r];
    }
}

// ---------------- GEMM 128x16, output scaled by dinv[row] ----------------
__global__ __launch_bounds__(256) void k_gemm16_scaled(
    const float* __restrict__ X, const float* __restrict__ W,
    const float* __restrict__ dinv, float* __restrict__ Y) {
    __shared__ float Wl[128 * 16];
    __shared__ float Xs[64 * 128];
    int t = threadIdx.x;
    {
        const float4* Wv = (const float4*)W;
        float4* Wlv = (float4*)Wl;
        for (int i = t; i < 512; i += 256) Wlv[i] = Wv[i];
    }
    int row0 = blockIdx.x * 64;
    int nrow = min(64, NN - row0);
    {
        const float4* Xv = (const float4*)(X + (size_t)row0 * 128);
        float4* Xsv = (float4*)Xs;
        for (int i = t; i < nrow * 32; i += 256) Xsv[i] = Xv[i];
    }
    __syncthreads();
    int c = t & 15;
    int rl = t >> 4;
    float acc[4] = {0.f, 0.f, 0.f, 0.f};
    for (int k = 0; k < 128; ++k) {
        float w = Wl[k * 16 + c];
#pragma unroll
        for (int j = 0; j < 4; ++j) acc[j] += Xs[(rl + j * 16) * 128 + k] * w;
    }
#pragma unroll
    for (int j = 0; j < 4; ++j) {
        int r = rl + j * 16;
        if (r < nrow) Y[(size_t)(row0 + r) * 16 + c] = acc[j] * dinv[row0 + r];
    }
}

// ---------------- aggregate 128ch (gather CSR) + bias + BN + ReLU ----------------
// 32 lanes per node, 8 nodes per 256-block. acc = Ts[node] + sum Ts[src].
__global__ __launch_bounds__(256) void k_agg128_bnrelu(
    const float* __restrict__ Ts, const int* __restrict__ rowptr,
    const int* __restrict__ eidx, const float* __restrict__ dinv,
    const float* __restrict__ b, const float* __restrict__ g,
    const float* __restrict__ beta, const float* __restrict__ m,
    const float* __restrict__ v, float* __restrict__ Z) {
    int node = blockIdx.x * 8 + (threadIdx.x >> 5);
    if (node >= NN) return;
    int lane = threadIdx.x & 31;
    const float4* Tv = (const float4*)Ts;
    float4 acc = Tv[node * 32 + lane];  // self-loop contribution
    int e0 = rowptr[node], e1 = rowptr[node + 1];
    for (int e = e0; e < e1; ++e) {
        int s = eidx[e];
        float4 t = Tv[s * 32 + lane];
        acc.x += t.x; acc.y += t.y; acc.z += t.z; acc.w += t.w;
    }
    float di = dinv[node];
    float4 bb = ((const float4*)b)[lane];
    float4 gg = ((const float4*)g)[lane];
    float4 be = ((const float4*)beta)[lane];
    float4 mm = ((const float4*)m)[lane];
    float4 vv = ((const float4*)v)[lane];
    float4 r;
    {
        float h = acc.x * di + bb.x;
        r.x = fmaxf((h - mm.x) * rsqrtf(vv.x + BN_EPS) * gg.x + be.x, 0.f);
    }
    {
        float h = acc.y * di + bb.y;
        r.y = fmaxf((h - mm.y) * rsqrtf(vv.y + BN_EPS) * gg.y + be.y, 0.f);
    }
    {
        float h = acc.z * di + bb.z;
        r.z = fmaxf((h - mm.z) * rsqrtf(vv.z + BN_EPS) * gg.z + be.z, 0.f);
    }
    {
        float h = acc.w * di + bb.w;
        r.w = fmaxf((h - mm.w) * rsqrtf(vv.w + BN_EPS) * gg.w + be.w, 0.f);
    }
    ((float4*)Z)[node * 32 + lane] = r;
}

// ---------------- aggregate 16ch + bias + log_softmax ----------------
// 4 lanes per node, 64 nodes per 256-block.
__global__ __launch_bounds__(256) void k_agg16_lsm(
    const float* __restrict__ Tc, const int* __restrict__ rowptr,
    const int* __restrict__ eidx, const float* __restrict__ dinv,
    const float* __restrict__ b3, float* __restrict__ out) {
    int node = blockIdx.x * 64 + (threadIdx.x >> 2);
    if (node >= NN) return;
    int lane = threadIdx.x & 3;
    const float4* Tv = (const float4*)Tc;
    float4 acc = Tv[node * 4 + lane];  // self-loop
    int e0 = rowptr[node], e1 = rowptr[node + 1];
    for (int e = e0; e < e1; ++e) {
        int s = eidx[e];
        float4 t = Tv[s * 4 + lane];
        acc.x += t.x; acc.y += t.y; acc.z += t.z; acc.w += t.w;
    }
    float di = dinv[node];
    float4 bb = ((const float4*)b3)[lane];
    float l0 = acc.x * di + bb.x;
    float l1 = acc.y * di + bb.y;
    float l2 = acc.z * di + bb.z;
    float l3 = acc.w * di + bb.w;
    float mx = fmaxf(fmaxf(l0, l1), fmaxf(l2, l3));
    mx = fmaxf(mx, __shfl_xor(mx, 1));
    mx = fmaxf(mx, __shfl_xor(mx, 2));
    float se = expf(l0 - mx) + expf(l1 - mx) + expf(l2 - mx) + expf(l3 - mx);
    se += __shfl_xor(se, 1);
    se += __shfl_xor(se, 2);
    float lse = mx + logf(se);
    ((float4*)out)[node * 4 + lane] = make_float4(l0 - lse, l1 - lse, l2 - lse, l3 - lse);
}

extern "C" void kernel_launch(void* const* d_in, const int* in_sizes, int n_in,
                              void* d_out, int out_size, void* d_ws, size_t ws_size,
                              hipStream_t stream) {
    const float* x  = (const float*)d_in[0];
    const int* ei   = (const int*)d_in[1];
    const float* W1 = (const float*)d_in[2];
    const float* b1 = (const float*)d_in[3];
    const float* g1 = (const float*)d_in[4];
    const float* be1 = (const float*)d_in[5];
    const float* m1 = (const float*)d_in[6];
    const float* v1 = (const float*)d_in[7];
    const float* W2 = (const float*)d_in[8];
    const float* b2 = (const float*)d_in[9];
    const float* g2 = (const float*)d_in[10];
    const float* be2 = (const float*)d_in[11];
    const float* m2 = (const float*)d_in[12];
    const float* v2 = (const float*)d_in[13];
    const float* W3 = (const float*)d_in[14];
    const float* b3 = (const float*)d_in[15];
    float* out = (float*)d_out;

    char* ws = (char*)d_ws;
    size_t off = 0;
    auto alloc = [&](size_t bytes) {
        char* p = ws + off;
        off = (off + bytes + 255) & ~255ULL;
        return p;
    };
    float* dinv  = (float*)alloc((size_t)NN * 4);
    int* degi    = (int*)alloc((size_t)NN * 4);
    int* rowptr  = (int*)alloc((size_t)(NN + 1) * 4);
    int* cursor  = (int*)alloc((size_t)NN * 4);
    int* bsum    = (int*)alloc(256 * 4);
    int* eidx    = (int*)alloc((size_t)NE * 4);
    float* bufA  = (float*)alloc((size_t)NN * 128 * 4);
    float* bufB  = (float*)alloc((size_t)NN * 128 * 4);
    float* bufC  = (float*)alloc((size_t)NN * 16 * 4);

    const int* srcp = ei;
    const int* dstp = ei + NE;

    // degree + dinv
    hipMemsetAsync(degi, 0, (size_t)NN * 4, stream);
    k_deg<<<(NE + 255) / 256, 256, 0, stream>>>(dstp, degi);
    k_dinv<<<(NN + 255) / 256, 256, 0, stream>>>(degi, dinv);

    // CSR build
    k_scan1<<<NB, 256, 0, stream>>>(degi, rowptr, bsum);
    k_scan2<<<1, 256, 0, stream>>>(bsum);
    k_scan3<<<NB, 256, 0, stream>>>(rowptr, bsum, cursor);
    k_csrfill<<<(NE + 255) / 256, 256, 0, stream>>>(srcp, dstp, cursor, eidx);

    // ---- layer 1 ----
    k_gemm128_scaled<<<(NN + 31) / 32, 256, 0, stream>>>(x, W1, dinv, bufA);
    k_agg128_bnrelu<<<(NN + 7) / 8, 256, 0, stream>>>(bufA, rowptr, eidx, dinv,
                                                      b1, g1, be1, m1, v1, bufB);

    // ---- layer 2 ----
    k_gemm128_scaled<<<(NN + 31) / 32, 256, 0, stream>>>(bufB, W2, dinv, bufA);
    k_agg128_bnrelu<<<(NN + 7) / 8, 256, 0, stream>>>(bufA, rowptr, eidx, dinv,
                                                      b2, g2, be2, m2, v2, bufB);

    // ---- layer 3 ----
    k_gemm16_scaled<<<(NN + 63) / 64, 256, 0, stream>>>(bufB, W3, dinv, bufC);
    k_agg16_lsm<<<(NN + 63) / 64, 256, 0, stream>>>(bufC, rowptr, eidx, dinv, b3, out);
}

// Round 3
// 321.466 us; speedup vs baseline: 9.8357x; 1.4905x over previous
//
#include <hip/hip_runtime.h>

#define NN 50000
#define NE 800000
#define NB 196          // (NN+255)/256
#define BN_EPS 1e-5f

typedef __attribute__((ext_vector_type(8))) short short8;
typedef __attribute__((ext_vector_type(16))) float f32x16;
typedef __attribute__((ext_vector_type(4))) float f32x4;

static __device__ __forceinline__ unsigned short f2bf(float f) {
    union { float f; unsigned u; } v; v.f = f;
    unsigned r = (v.u + 0x7FFF + ((v.u >> 16) & 1)) >> 16;
    return (unsigned short)r;
}
static __device__ __forceinline__ float bf2f(unsigned short s) {
    union { unsigned u; float f; } v; v.u = ((unsigned)s) << 16;
    return v.f;
}

// ---------------- degree ----------------
__global__ void k_deg(const int* __restrict__ dst, int* __restrict__ deg) {
    int e = blockIdx.x * blockDim.x + threadIdx.x;
    if (e < NE) atomicAdd(&deg[dst[e]], 1);
}

__global__ void k_dinv(const int* __restrict__ deg, float* __restrict__ dinv) {
    int i = blockIdx.x * blockDim.x + threadIdx.x;
    if (i < NN) dinv[i] = rsqrtf((float)(deg[i] + 1));  // +1 self-loop
}

// ---------------- BN fold: sc = rsqrt(v+eps)*g ; sh = beta + (b-m)*sc ----------------
__global__ void k_bnprep(const float* b1, const float* g1, const float* be1,
                         const float* m1, const float* v1,
                         const float* b2, const float* g2, const float* be2,
                         const float* m2, const float* v2,
                         float* sc1, float* sh1, float* sc2, float* sh2) {
    int c = threadIdx.x;
    if (c < 128) {
        float s1 = rsqrtf(v1[c] + BN_EPS) * g1[c];
        sc1[c] = s1; sh1[c] = be1[c] + (b1[c] - m1[c]) * s1;
        float s2 = rsqrtf(v2[c] + BN_EPS) * g2[c];
        sc2[c] = s2; sh2[c] = be2[c] + (b2[c] - m2[c]) * s2;
    }
}

// ---------------- exclusive scan (3-kernel hierarchical) ----------------
__global__ __launch_bounds__(256) void k_scan1(const int* __restrict__ deg,
                                               int* __restrict__ rowptr,
                                               int* __restrict__ bsum) {
    __shared__ int s[256];
    int t = threadIdx.x;
    int i = blockIdx.x * 256 + t;
    int v = (i < NN) ? deg[i] : 0;
    s[t] = v;
    __syncthreads();
    for (int off = 1; off < 256; off <<= 1) {
        int add = (t >= off) ? s[t - off] : 0;
        __syncthreads();
        s[t] += add;
        __syncthreads();
    }
    if (i < NN) rowptr[i] = s[t] - v;
    if (t == 255) bsum[blockIdx.x] = s[255];
}

__global__ __launch_bounds__(256) void k_scan2(int* __restrict__ bsum) {
    __shared__ int s[256];
    int t = threadIdx.x;
    int v = (t < NB) ? bsum[t] : 0;
    s[t] = v;
    __syncthreads();
    for (int off = 1; off < 256; off <<= 1) {
        int add = (t >= off) ? s[t - off] : 0;
        __syncthreads();
        s[t] += add;
        __syncthreads();
    }
    if (t < NB) bsum[t] = s[t] - v;
}

__global__ __launch_bounds__(256) void k_scan3(int* __restrict__ rowptr,
                                               const int* __restrict__ bsum,
                                               int* __restrict__ cursor) {
    int i = blockIdx.x * 256 + threadIdx.x;
    if (i < NN) {
        int r = rowptr[i] + bsum[blockIdx.x];
        rowptr[i] = r;
        cursor[i] = r;
    }
    if (i == 0) rowptr[NN] = NE;
}

__global__ void k_csrfill(const int* __restrict__ src, const int* __restrict__ dst,
                          int* __restrict__ cursor, int* __restrict__ eidx) {
    int e = blockIdx.x * blockDim.x + threadIdx.x;
    if (e >= NE) return;
    int d = dst[e];
    int pos = atomicAdd(&cursor[d], 1);
    eidx[pos] = src[e];
}

// ---------------- MFMA GEMM 128->128, Y = bf16(dinv[row] * (X @ W)) ----------------
// 256 thr = 4 waves; block covers 128 rows (wave w: rows w*32..w*32+31).
// mfma_f32_32x32x16_bf16: A[m=l&31][k=(l>>5)*8+j]; B[k][n=l&31]; D col=l&31,row=(r&3)+8*(r>>2)+4*(l>>5)
template <int ISF>
__global__ __launch_bounds__(256) void k_mfma_gemm128(
    const void* __restrict__ Xv, const float* __restrict__ W,
    const float* __restrict__ dinv, unsigned short* __restrict__ Y) {
    __shared__ unsigned short Wt[128 * 136];  // [n][k], stride 136 (16B-aligned, 4-way max)
    int t = threadIdx.x;
    for (int i = t; i < 16384; i += 256) {
        int k = i >> 7, n = i & 127;
        Wt[n * 136 + k] = f2bf(W[i]);
    }
    __syncthreads();

    int wv = t >> 6;
    int l = t & 63;
    int l31 = l & 31;
    int khalf = l >> 5;      // 0/1
    int rowb = blockIdx.x * 128 + wv * 32;
    int myrow = rowb + l31;
    int rowc = myrow < NN ? myrow : NN - 1;  // clamp loads

    f32x16 acc[4];
#pragma unroll
    for (int nt = 0; nt < 4; ++nt)
#pragma unroll
        for (int r = 0; r < 16; ++r) acc[nt][r] = 0.f;

#pragma unroll
    for (int ks = 0; ks < 8; ++ks) {
        int kk = ks * 16;
        short8 a;
        if (ISF) {
            const float* ap = (const float*)Xv + (size_t)rowc * 128 + kk + khalf * 8;
            float4 f0 = ((const float4*)ap)[0];
            float4 f1 = ((const float4*)ap)[1];
            a[0] = (short)f2bf(f0.x); a[1] = (short)f2bf(f0.y);
            a[2] = (short)f2bf(f0.z); a[3] = (short)f2bf(f0.w);
            a[4] = (short)f2bf(f1.x); a[5] = (short)f2bf(f1.y);
            a[6] = (short)f2bf(f1.z); a[7] = (short)f2bf(f1.w);
        } else {
            a = *(const short8*)((const unsigned short*)Xv + (size_t)rowc * 128 + kk + khalf * 8);
        }
#pragma unroll
        for (int nt = 0; nt < 4; ++nt) {
            short8 b = *(const short8*)&Wt[(nt * 32 + l31) * 136 + kk + khalf * 8];
            acc[nt] = __builtin_amdgcn_mfma_f32_32x32x16_bf16(a, b, acc[nt], 0, 0, 0);
        }
    }

#pragma unroll
    for (int r = 0; r < 16; ++r) {
        int m = (r & 3) + 8 * (r >> 2) + 4 * khalf;
        int grow = rowb + m;
        if (grow < NN) {
            float dsc = dinv[grow];
#pragma unroll
            for (int nt = 0; nt < 4; ++nt)
                Y[(size_t)grow * 128 + nt * 32 + l31] = f2bf(acc[nt][r] * dsc);
        }
    }
}

// ---------------- MFMA GEMM 128->16, Y = bf16(dinv[row] * (X @ W3)) ----------------
// 256 thr = 4 waves; block covers 256 rows (wave w: rows w*64, 4 m-tiles of 16).
// mfma_f32_16x16x32_bf16: A[m=l&15][k=(l>>4)*8+j]; B[k][n=l&15]; D col=l&15,row=(l>>4)*4+r
__global__ __launch_bounds__(256) void k_mfma_gemm16(
    const unsigned short* __restrict__ Xb, const float* __restrict__ W3,
    const float* __restrict__ dinv, unsigned short* __restrict__ Y) {
    __shared__ unsigned short Wt[16 * 136];
    int t = threadIdx.x;
    for (int i = t; i < 2048; i += 256) {
        int k = i >> 4, n = i & 15;
        Wt[n * 136 + k] = f2bf(W3[i]);
    }
    __syncthreads();

    int wv = t >> 6;
    int l = t & 63;
    int l15 = l & 15;
    int quad = l >> 4;      // 0..3
    int rowb = blockIdx.x * 256 + wv * 64;

    f32x4 acc[4];
#pragma unroll
    for (int mt = 0; mt < 4; ++mt)
#pragma unroll
        for (int r = 0; r < 4; ++r) acc[mt][r] = 0.f;

#pragma unroll
    for (int ks = 0; ks < 4; ++ks) {
        int kk = ks * 32;
        short8 b = *(const short8*)&Wt[l15 * 136 + kk + quad * 8];
#pragma unroll
        for (int mt = 0; mt < 4; ++mt) {
            int row = rowb + mt * 16 + l15;
            int rowc = row < NN ? row : NN - 1;
            short8 a = *(const short8*)(Xb + (size_t)rowc * 128 + kk + quad * 8);
            acc[mt] = __builtin_amdgcn_mfma_f32_16x16x32_bf16(a, b, acc[mt], 0, 0, 0);
        }
    }

#pragma unroll
    for (int mt = 0; mt < 4; ++mt) {
#pragma unroll
        for (int r = 0; r < 4; ++r) {
            int grow = rowb + mt * 16 + quad * 4 + r;
            if (grow < NN)
                Y[(size_t)grow * 16 + l15] = f2bf(acc[mt][r] * dinv[grow]);
        }
    }
}

// ---------------- aggregate 128ch bf16 + folded-BN + ReLU ----------------
// 16 lanes/node (each lane: 8 channels via one float4=8 bf16), 16 nodes/block.
__global__ __launch_bounds__(256) void k_agg128_bnrelu(
    const unsigned short* __restrict__ Ts, const int* __restrict__ rowptr,
    const int* __restrict__ eidx, const float* __restrict__ dinv,
    const float* __restrict__ sc, const float* __restrict__ sh,
    unsigned short* __restrict__ Z) {
    int node = blockIdx.x * 16 + (threadIdx.x >> 4);
    int lane = threadIdx.x & 15;
    const float4* Tv = (const float4*)Ts;

    float4 sv = Tv[(size_t)node * 16 + lane];  // self-loop row chunk
    const unsigned short* su = (const unsigned short*)&sv;
    float acc[8];
#pragma unroll
    for (int j = 0; j < 8; ++j) acc[j] = bf2f(su[j]);

    int e0 = rowptr[node], e1 = rowptr[node + 1];
    for (int e = e0; e < e1; ++e) {
        int s = eidx[e];
        float4 gv = Tv[(size_t)s * 16 + lane];
        const unsigned short* gu = (const unsigned short*)&gv;
#pragma unroll
        for (int j = 0; j < 8; ++j) acc[j] += bf2f(gu[j]);
    }

    float di = dinv[node];
    float4 sc0 = ((const float4*)sc)[lane * 2 + 0];
    float4 sc1 = ((const float4*)sc)[lane * 2 + 1];
    float4 sh0 = ((const float4*)sh)[lane * 2 + 0];
    float4 sh1 = ((const float4*)sh)[lane * 2 + 1];
    float scl[8] = {sc0.x, sc0.y, sc0.z, sc0.w, sc1.x, sc1.y, sc1.z, sc1.w};
    float shl[8] = {sh0.x, sh0.y, sh0.z, sh0.w, sh1.x, sh1.y, sh1.z, sh1.w};

    float4 outv;
    unsigned short* ou = (unsigned short*)&outv;
#pragma unroll
    for (int j = 0; j < 8; ++j)
        ou[j] = f2bf(fmaxf(acc[j] * di * scl[j] + shl[j], 0.f));
    ((float4*)Z)[(size_t)node * 16 + lane] = outv;
}

// ---------------- aggregate 16ch bf16 + bias + log_softmax -> fp32 out ----------------
// 2 lanes/node (each lane: 8 channels), 128 nodes/block.
__global__ __launch_bounds__(256) void k_agg16_lsm(
    const unsigned short* __restrict__ Tc, const int* __restrict__ rowptr,
    const int* __restrict__ eidx, const float* __restrict__ dinv,
    const float* __restrict__ b3, float* __restrict__ out) {
    int node = blockIdx.x * 128 + (threadIdx.x >> 1);
    if (node >= NN) return;
    int half = threadIdx.x & 1;
    const float4* Tv = (const float4*)Tc;

    float4 sv = Tv[(size_t)node * 2 + half];
    const unsigned short* su = (const unsigned short*)&sv;
    float acc[8];
#pragma unroll
    for (int j = 0; j < 8; ++j) acc[j] = bf2f(su[j]);

    int e0 = rowptr[node], e1 = rowptr[node + 1];
    for (int e = e0; e < e1; ++e) {
        int s = eidx[e];
        float4 gv = Tv[(size_t)s * 2 + half];
        const unsigned short* gu = (const unsigned short*)&gv;
#pragma unroll
        for (int j = 0; j < 8; ++j) acc[j] += bf2f(gu[j]);
    }

    float di = dinv[node];
    float4 b0 = ((const float4*)b3)[half * 2 + 0];
    float4 b1 = ((const float4*)b3)[half * 2 + 1];
    float bl[8] = {b0.x, b0.y, b0.z, b0.w, b1.x, b1.y, b1.z, b1.w};
    float lg[8];
    float mx = -1e30f;
#pragma unroll
    for (int j = 0; j < 8; ++j) {
        lg[j] = acc[j] * di + bl[j];
        mx = fmaxf(mx, lg[j]);
    }
    mx = fmaxf(mx, __shfl_xor(mx, 1));
    float se = 0.f;
#pragma unroll
    for (int j = 0; j < 8; ++j) se += expf(lg[j] - mx);
    se += __shfl_xor(se, 1);
    float lse = mx + logf(se);
    float4 o0 = make_float4(lg[0] - lse, lg[1] - lse, lg[2] - lse, lg[3] - lse);
    float4 o1 = make_float4(lg[4] - lse, lg[5] - lse, lg[6] - lse, lg[7] - lse);
    ((float4*)out)[(size_t)node * 4 + half * 2 + 0] = o0;
    ((float4*)out)[(size_t)node * 4 + half * 2 + 1] = o1;
}

extern "C" void kernel_launch(void* const* d_in, const int* in_sizes, int n_in,
                              void* d_out, int out_size, void* d_ws, size_t ws_size,
                              hipStream_t stream) {
    const float* x  = (const float*)d_in[0];
    const int* ei   = (const int*)d_in[1];
    const float* W1 = (const float*)d_in[2];
    const float* b1 = (const float*)d_in[3];
    const float* g1 = (const float*)d_in[4];
    const float* be1 = (const float*)d_in[5];
    const float* m1 = (const float*)d_in[6];
    const float* v1 = (const float*)d_in[7];
    const float* W2 = (const float*)d_in[8];
    const float* b2 = (const float*)d_in[9];
    const float* g2 = (const float*)d_in[10];
    const float* be2 = (const float*)d_in[11];
    const float* m2 = (const float*)d_in[12];
    const float* v2 = (const float*)d_in[13];
    const float* W3 = (const float*)d_in[14];
    const float* b3 = (const float*)d_in[15];
    float* out = (float*)d_out;

    char* ws = (char*)d_ws;
    size_t off = 0;
    auto alloc = [&](size_t bytes) {
        char* p = ws + off;
        off = (off + bytes + 255) & ~255ULL;
        return p;
    };
    float* dinv  = (float*)alloc((size_t)NN * 4);
    int* degi    = (int*)alloc((size_t)NN * 4);
    int* rowptr  = (int*)alloc((size_t)(NN + 1) * 4);
    int* cursor  = (int*)alloc((size_t)NN * 4);
    int* bsum    = (int*)alloc(256 * 4);
    int* eidx    = (int*)alloc((size_t)NE * 4);
    float* sc1   = (float*)alloc(128 * 4);
    float* sh1   = (float*)alloc(128 * 4);
    float* sc2   = (float*)alloc(128 * 4);
    float* sh2   = (float*)alloc(128 * 4);
    unsigned short* TsA = (unsigned short*)alloc((size_t)NN * 128 * 2);
    unsigned short* actB = (unsigned short*)alloc((size_t)NN * 128 * 2);
    unsigned short* TcC = (unsigned short*)alloc((size_t)NN * 16 * 2);

    const int* srcp = ei;
    const int* dstp = ei + NE;

    // degree + dinv + CSR + BN fold
    hipMemsetAsync(degi, 0, (size_t)NN * 4, stream);
    k_deg<<<(NE + 255) / 256, 256, 0, stream>>>(dstp, degi);
    k_dinv<<<(NN + 255) / 256, 256, 0, stream>>>(degi, dinv);
    k_scan1<<<NB, 256, 0, stream>>>(degi, rowptr, bsum);
    k_scan2<<<1, 256, 0, stream>>>(bsum);
    k_scan3<<<NB, 256, 0, stream>>>(rowptr, bsum, cursor);
    k_csrfill<<<(NE + 255) / 256, 256, 0, stream>>>(srcp, dstp, cursor, eidx);
    k_bnprep<<<1, 128, 0, stream>>>(b1, g1, be1, m1, v1, b2, g2, be2, m2, v2,
                                    sc1, sh1, sc2, sh2);

    // ---- layer 1 ----
    k_mfma_gemm128<1><<<(NN + 127) / 128, 256, 0, stream>>>(x, W1, dinv, TsA);
    k_agg128_bnrelu<<<NN / 16, 256, 0, stream>>>(TsA, rowptr, eidx, dinv, sc1, sh1, actB);

    // ---- layer 2 ----
    k_mfma_gemm128<0><<<(NN + 127) / 128, 256, 0, stream>>>(actB, W2, dinv, TsA);
    k_agg128_bnrelu<<<NN / 16, 256, 0, stream>>>(TsA, rowptr, eidx, dinv, sc2, sh2, actB);

    // ---- layer 3 ----
    k_mfma_gemm16<<<(NN + 255) / 256, 256, 0, stream>>>(actB, W3, dinv, TcC);
    k_agg16_lsm<<<(NN + 127) / 128, 256, 0, stream>>>(TcC, rowptr, eidx, dinv, b3, out);
}

// Round 4
// 279.527 us; speedup vs baseline: 11.3114x; 1.1500x over previous
//
#include <hip/hip_runtime.h>

#define NN 50000
#define NE 800000
#define NB 196          // (NN+255)/256
#define BN_EPS 1e-5f

typedef __attribute__((ext_vector_type(8))) short short8;
typedef __attribute__((ext_vector_type(16))) float f32x16;
typedef __attribute__((ext_vector_type(4))) float f32x4;

static __device__ __forceinline__ unsigned short f2bf(float f) {
    union { float f; unsigned u; } v; v.f = f;
    unsigned r = (v.u + 0x7FFF + ((v.u >> 16) & 1)) >> 16;
    return (unsigned short)r;
}
static __device__ __forceinline__ float bf2f(unsigned short s) {
    union { unsigned u; float f; } v; v.u = ((unsigned)s) << 16;
    return v.f;
}

// ---------------- degree + per-edge rank (atomic return value kept) ----------------
__global__ void k_deg_rank(const int* __restrict__ dst, int* __restrict__ deg,
                           int* __restrict__ rank) {
    int e = blockIdx.x * blockDim.x + threadIdx.x;
    if (e < NE) rank[e] = atomicAdd(&deg[dst[e]], 1);
}

// ---------------- BN fold: sc = rsqrt(v+eps)*g ; sh = beta + (b-m)*sc ----------------
__global__ void k_bnprep(const float* b1, const float* g1, const float* be1,
                         const float* m1, const float* v1,
                         const float* b2, const float* g2, const float* be2,
                         const float* m2, const float* v2,
                         float* sc1, float* sh1, float* sc2, float* sh2) {
    int c = threadIdx.x;
    if (c < 128) {
        float s1 = rsqrtf(v1[c] + BN_EPS) * g1[c];
        sc1[c] = s1; sh1[c] = be1[c] + (b1[c] - m1[c]) * s1;
        float s2 = rsqrtf(v2[c] + BN_EPS) * g2[c];
        sc2[c] = s2; sh2[c] = be2[c] + (b2[c] - m2[c]) * s2;
    }
}

// ---------------- exclusive scan (3-kernel hierarchical), dinv fused ----------------
__global__ __launch_bounds__(256) void k_scan1(const int* __restrict__ deg,
                                               int* __restrict__ rowptr,
                                               int* __restrict__ bsum,
                                               float* __restrict__ dinv) {
    __shared__ int s[256];
    int t = threadIdx.x;
    int i = blockIdx.x * 256 + t;
    int v = (i < NN) ? deg[i] : 0;
    if (i < NN) dinv[i] = rsqrtf((float)(v + 1));  // +1 self-loop
    s[t] = v;
    __syncthreads();
    for (int off = 1; off < 256; off <<= 1) {
        int add = (t >= off) ? s[t - off] : 0;
        __syncthreads();
        s[t] += add;
        __syncthreads();
    }
    if (i < NN) rowptr[i] = s[t] - v;
    if (t == 255) bsum[blockIdx.x] = s[255];
}

__global__ __launch_bounds__(256) void k_scan2(int* __restrict__ bsum) {
    __shared__ int s[256];
    int t = threadIdx.x;
    int v = (t < NB) ? bsum[t] : 0;
    s[t] = v;
    __syncthreads();
    for (int off = 1; off < 256; off <<= 1) {
        int add = (t >= off) ? s[t - off] : 0;
        __syncthreads();
        s[t] += add;
        __syncthreads();
    }
    if (t < NB) bsum[t] = s[t] - v;
}

__global__ __launch_bounds__(256) void k_scan3(int* __restrict__ rowptr,
                                               const int* __restrict__ bsum) {
    int i = blockIdx.x * 256 + threadIdx.x;
    if (i < NN) rowptr[i] += bsum[blockIdx.x];
    if (i == 0) rowptr[NN] = NE;
}

// ---------------- CSR fill: no atomics (uses precomputed rank) ----------------
__global__ void k_fill(const int* __restrict__ src, const int* __restrict__ dst,
                       const int* __restrict__ rowptr, const int* __restrict__ rank,
                       int* __restrict__ eidx) {
    int e = blockIdx.x * blockDim.x + threadIdx.x;
    if (e >= NE) return;
    eidx[rowptr[dst[e]] + rank[e]] = src[e];
}

// ---------------- MFMA GEMM 128->128, Y = bf16(dinv[row] * (X @ W)) ----------------
template <int ISF>
__global__ __launch_bounds__(256) void k_mfma_gemm128(
    const void* __restrict__ Xv, const float* __restrict__ W,
    const float* __restrict__ dinv, unsigned short* __restrict__ Y) {
    __shared__ unsigned short Wt[128 * 136];  // [n][k]
    int t = threadIdx.x;
    for (int i = t; i < 16384; i += 256) {
        int k = i >> 7, n = i & 127;
        Wt[n * 136 + k] = f2bf(W[i]);
    }
    __syncthreads();

    int wv = t >> 6;
    int l = t & 63;
    int l31 = l & 31;
    int khalf = l >> 5;
    int rowb = blockIdx.x * 128 + wv * 32;
    int myrow = rowb + l31;
    int rowc = myrow < NN ? myrow : NN - 1;

    f32x16 acc[4];
#pragma unroll
    for (int nt = 0; nt < 4; ++nt)
#pragma unroll
        for (int r = 0; r < 16; ++r) acc[nt][r] = 0.f;

#pragma unroll
    for (int ks = 0; ks < 8; ++ks) {
        int kk = ks * 16;
        short8 a;
        if (ISF) {
            const float* ap = (const float*)Xv + (size_t)rowc * 128 + kk + khalf * 8;
            float4 f0 = ((const float4*)ap)[0];
            float4 f1 = ((const float4*)ap)[1];
            a[0] = (short)f2bf(f0.x); a[1] = (short)f2bf(f0.y);
            a[2] = (short)f2bf(f0.z); a[3] = (short)f2bf(f0.w);
            a[4] = (short)f2bf(f1.x); a[5] = (short)f2bf(f1.y);
            a[6] = (short)f2bf(f1.z); a[7] = (short)f2bf(f1.w);
        } else {
            a = *(const short8*)((const unsigned short*)Xv + (size_t)rowc * 128 + kk + khalf * 8);
        }
#pragma unroll
        for (int nt = 0; nt < 4; ++nt) {
            short8 b = *(const short8*)&Wt[(nt * 32 + l31) * 136 + kk + khalf * 8];
            acc[nt] = __builtin_amdgcn_mfma_f32_32x32x16_bf16(a, b, acc[nt], 0, 0, 0);
        }
    }

#pragma unroll
    for (int r = 0; r < 16; ++r) {
        int m = (r & 3) + 8 * (r >> 2) + 4 * khalf;
        int grow = rowb + m;
        if (grow < NN) {
            float dsc = dinv[grow];
#pragma unroll
            for (int nt = 0; nt < 4; ++nt)
                Y[(size_t)grow * 128 + nt * 32 + l31] = f2bf(acc[nt][r] * dsc);
        }
    }
}

// ---------------- MFMA GEMM 128->16 ----------------
__global__ __launch_bounds__(256) void k_mfma_gemm16(
    const unsigned short* __restrict__ Xb, const float* __restrict__ W3,
    const float* __restrict__ dinv, unsigned short* __restrict__ Y) {
    __shared__ unsigned short Wt[16 * 136];
    int t = threadIdx.x;
    for (int i = t; i < 2048; i += 256) {
        int k = i >> 4, n = i & 15;
        Wt[n * 136 + k] = f2bf(W3[i]);
    }
    __syncthreads();

    int wv = t >> 6;
    int l = t & 63;
    int l15 = l & 15;
    int quad = l >> 4;
    int rowb = blockIdx.x * 256 + wv * 64;

    f32x4 acc[4];
#pragma unroll
    for (int mt = 0; mt < 4; ++mt)
#pragma unroll
        for (int r = 0; r < 4; ++r) acc[mt][r] = 0.f;

#pragma unroll
    for (int ks = 0; ks < 4; ++ks) {
        int kk = ks * 32;
        short8 b = *(const short8*)&Wt[l15 * 136 + kk + quad * 8];
#pragma unroll
        for (int mt = 0; mt < 4; ++mt) {
            int row = rowb + mt * 16 + l15;
            int rowc = row < NN ? row : NN - 1;
            short8 a = *(const short8*)(Xb + (size_t)rowc * 128 + kk + quad * 8);
            acc[mt] = __builtin_amdgcn_mfma_f32_16x16x32_bf16(a, b, acc[mt], 0, 0, 0);
        }
    }

#pragma unroll
    for (int mt = 0; mt < 4; ++mt) {
#pragma unroll
        for (int r = 0; r < 4; ++r) {
            int grow = rowb + mt * 16 + quad * 4 + r;
            if (grow < NN)
                Y[(size_t)grow * 16 + l15] = f2bf(acc[mt][r] * dinv[grow]);
        }
    }
}

// ---------------- aggregate 128ch: 1 node/wave, 4 edge-slots x 16 ch-lanes ----------------
__global__ __launch_bounds__(256) void k_agg128_bnrelu(
    const unsigned short* __restrict__ Ts, const int* __restrict__ rowptr,
    const int* __restrict__ eidx, const float* __restrict__ dinv,
    const float* __restrict__ sc, const float* __restrict__ sh,
    unsigned short* __restrict__ Z) {
    int node = blockIdx.x * 4 + (threadIdx.x >> 6);
    int l = threadIdx.x & 63;
    int grp = l >> 4;       // edge slot 0..3
    int lane = l & 15;      // channel chunk (8 ch)
    const float4* Tv = (const float4*)Ts;

    float acc[8];
    if (grp == 0) {
        float4 sv = Tv[(size_t)node * 16 + lane];  // self-loop
        const unsigned short* su = (const unsigned short*)&sv;
#pragma unroll
        for (int j = 0; j < 8; ++j) acc[j] = bf2f(su[j]);
    } else {
#pragma unroll
        for (int j = 0; j < 8; ++j) acc[j] = 0.f;
    }

    int e0 = rowptr[node], e1 = rowptr[node + 1];
    for (int e = e0 + grp; e < e1; e += 4) {
        int s = eidx[e];
        float4 gv = Tv[(size_t)s * 16 + lane];
        const unsigned short* gu = (const unsigned short*)&gv;
#pragma unroll
        for (int j = 0; j < 8; ++j) acc[j] += bf2f(gu[j]);
    }

    // reduce across the 4 edge slots (lane bits 4,5)
#pragma unroll
    for (int j = 0; j < 8; ++j) {
        acc[j] += __shfl_xor(acc[j], 16);
        acc[j] += __shfl_xor(acc[j], 32);
    }

    if (grp == 0) {
        float di = dinv[node];
        float4 sc0 = ((const float4*)sc)[lane * 2 + 0];
        float4 sc1 = ((const float4*)sc)[lane * 2 + 1];
        float4 sh0 = ((const float4*)sh)[lane * 2 + 0];
        float4 sh1 = ((const float4*)sh)[lane * 2 + 1];
        float scl[8] = {sc0.x, sc0.y, sc0.z, sc0.w, sc1.x, sc1.y, sc1.z, sc1.w};
        float shl[8] = {sh0.x, sh0.y, sh0.z, sh0.w, sh1.x, sh1.y, sh1.z, sh1.w};
        float4 outv;
        unsigned short* ou = (unsigned short*)&outv;
#pragma unroll
        for (int j = 0; j < 8; ++j)
            ou[j] = f2bf(fmaxf(acc[j] * di * scl[j] + shl[j], 0.f));
        ((float4*)Z)[(size_t)node * 16 + lane] = outv;
    }
}

// ---------------- aggregate 16ch: 8 lanes/node (4 edge-slots x 2 ch-lanes) + lsm ----------------
__global__ __launch_bounds__(256) void k_agg16_lsm(
    const unsigned short* __restrict__ Tc, const int* __restrict__ rowptr,
    const int* __restrict__ eidx, const float* __restrict__ dinv,
    const float* __restrict__ b3, float* __restrict__ out) {
    int node = blockIdx.x * 32 + (threadIdx.x >> 3);
    if (node >= NN) return;
    int sub = threadIdx.x & 7;
    int grp = sub >> 1;     // edge slot 0..3 (lane bits 1,2)
    int half = sub & 1;     // channel chunk (8 ch)
    const float4* Tv = (const float4*)Tc;

    float acc[8];
    if (grp == 0) {
        float4 sv = Tv[(size_t)node * 2 + half];
        const unsigned short* su = (const unsigned short*)&sv;
#pragma unroll
        for (int j = 0; j < 8; ++j) acc[j] = bf2f(su[j]);
    } else {
#pragma unroll
        for (int j = 0; j < 8; ++j) acc[j] = 0.f;
    }

    int e0 = rowptr[node], e1 = rowptr[node + 1];
    for (int e = e0 + grp; e < e1; e += 4) {
        int s = eidx[e];
        float4 gv = Tv[(size_t)s * 2 + half];
        const unsigned short* gu = (const unsigned short*)&gv;
#pragma unroll
        for (int j = 0; j < 8; ++j) acc[j] += bf2f(gu[j]);
    }

#pragma unroll
    for (int j = 0; j < 8; ++j) {
        acc[j] += __shfl_xor(acc[j], 2);
        acc[j] += __shfl_xor(acc[j], 4);
    }

    if (grp == 0) {
        float di = dinv[node];
        float4 b0 = ((const float4*)b3)[half * 2 + 0];
        float4 b1 = ((const float4*)b3)[half * 2 + 1];
        float bl[8] = {b0.x, b0.y, b0.z, b0.w, b1.x, b1.y, b1.z, b1.w};
        float lg[8];
        float mx = -1e30f;
#pragma unroll
        for (int j = 0; j < 8; ++j) {
            lg[j] = acc[j] * di + bl[j];
            mx = fmaxf(mx, lg[j]);
        }
        mx = fmaxf(mx, __shfl_xor(mx, 1));
        float se = 0.f;
#pragma unroll
        for (int j = 0; j < 8; ++j) se += expf(lg[j] - mx);
        se += __shfl_xor(se, 1);
        float lse = mx + logf(se);
        float4 o0 = make_float4(lg[0] - lse, lg[1] - lse, lg[2] - lse, lg[3] - lse);
        float4 o1 = make_float4(lg[4] - lse, lg[5] - lse, lg[6] - lse, lg[7] - lse);
        ((float4*)out)[(size_t)node * 4 + half * 2 + 0] = o0;
        ((float4*)out)[(size_t)node * 4 + half * 2 + 1] = o1;
    }
}

extern "C" void kernel_launch(void* const* d_in, const int* in_sizes, int n_in,
                              void* d_out, int out_size, void* d_ws, size_t ws_size,
                              hipStream_t stream) {
    const float* x  = (const float*)d_in[0];
    const int* ei   = (const int*)d_in[1];
    const float* W1 = (const float*)d_in[2];
    const float* b1 = (const float*)d_in[3];
    const float* g1 = (const float*)d_in[4];
    const float* be1 = (const float*)d_in[5];
    const float* m1 = (const float*)d_in[6];
    const float* v1 = (const float*)d_in[7];
    const float* W2 = (const float*)d_in[8];
    const float* b2 = (const float*)d_in[9];
    const float* g2 = (const float*)d_in[10];
    const float* be2 = (const float*)d_in[11];
    const float* m2 = (const float*)d_in[12];
    const float* v2 = (const float*)d_in[13];
    const float* W3 = (const float*)d_in[14];
    const float* b3 = (const float*)d_in[15];
    float* out = (float*)d_out;

    char* ws = (char*)d_ws;
    size_t off = 0;
    auto alloc = [&](size_t bytes) {
        char* p = ws + off;
        off = (off + bytes + 255) & ~255ULL;
        return p;
    };
    float* dinv  = (float*)alloc((size_t)NN * 4);
    int* degi    = (int*)alloc((size_t)NN * 4);
    int* rowptr  = (int*)alloc((size_t)(NN + 1) * 4);
    int* bsum    = (int*)alloc(256 * 4);
    int* rank    = (int*)alloc((size_t)NE * 4);
    int* eidx    = (int*)alloc((size_t)NE * 4);
    float* sc1   = (float*)alloc(128 * 4);
    float* sh1   = (float*)alloc(128 * 4);
    float* sc2   = (float*)alloc(128 * 4);
    float* sh2   = (float*)alloc(128 * 4);
    unsigned short* TsA = (unsigned short*)alloc((size_t)NN * 128 * 2);
    unsigned short* actB = (unsigned short*)alloc((size_t)NN * 128 * 2);
    unsigned short* TcC = (unsigned short*)alloc((size_t)NN * 16 * 2);

    const int* srcp = ei;
    const int* dstp = ei + NE;

    // degree/rank + dinv + CSR + BN fold
    hipMemsetAsync(degi, 0, (size_t)NN * 4, stream);
    k_deg_rank<<<(NE + 255) / 256, 256, 0, stream>>>(dstp, degi, rank);
    k_scan1<<<NB, 256, 0, stream>>>(degi, rowptr, bsum, dinv);
    k_scan2<<<1, 256, 0, stream>>>(bsum);
    k_scan3<<<NB, 256, 0, stream>>>(rowptr, bsum);
    k_fill<<<(NE + 255) / 256, 256, 0, stream>>>(srcp, dstp, rowptr, rank, eidx);
    k_bnprep<<<1, 128, 0, stream>>>(b1, g1, be1, m1, v1, b2, g2, be2, m2, v2,
                                    sc1, sh1, sc2, sh2);

    // ---- layer 1 ----
    k_mfma_gemm128<1><<<(NN + 127) / 128, 256, 0, stream>>>(x, W1, dinv, TsA);
    k_agg128_bnrelu<<<NN / 4, 256, 0, stream>>>(TsA, rowptr, eidx, dinv, sc1, sh1, actB);

    // ---- layer 2 ----
    k_mfma_gemm128<0><<<(NN + 127) / 128, 256, 0, stream>>>(actB, W2, dinv, TsA);
    k_agg128_bnrelu<<<NN / 4, 256, 0, stream>>>(TsA, rowptr, eidx, dinv, sc2, sh2, actB);

    // ---- layer 3 ----
    k_mfma_gemm16<<<(NN + 255) / 256, 256, 0, stream>>>(actB, W3, dinv, TcC);
    k_agg16_lsm<<<(NN + 31) / 32, 256, 0, stream>>>(TcC, rowptr, eidx, dinv, b3, out);
}